// Round 14
// baseline (73.344 us; speedup 1.0000x reference)
//
#include <hip/hip_runtime.h>
#include <hip/hip_bf16.h>
#include <math.h>

#define B_ 8
#define S_ 2048
#define H_ 4
#define DH_ 32
#define D_ 128
#define BS_ (B_ * S_)
#define LOG2E 1.4426950408889634f
#define QSCALE (0.17677669529663687f * LOG2E)

typedef float f32x4  __attribute__((ext_vector_type(4)));
typedef float f32x16 __attribute__((ext_vector_type(16)));
typedef short s16x8  __attribute__((ext_vector_type(8)));

__device__ __forceinline__ unsigned short bf(float x) {
    return __builtin_bit_cast(unsigned short, __float2bfloat16(x));
}
__device__ __forceinline__ float bf2f(unsigned short u) {
    return __builtin_bit_cast(float, (unsigned int)u << 16);
}
// v_cvt_pk_bf16_f32: dst.lo = bf16(a), dst.hi = bf16(b)  (1 VALU instr)
__device__ __forceinline__ unsigned int pk2(float a, float b) {
    unsigned int r;
    asm("v_cvt_pk_bf16_f32 %0, %1, %2" : "=v"(r) : "v"(a), "v"(b));
    return r;
}
// v_permlane32_swap_b32: a' = [a_lo | b_lo], b' = [a_hi | b_hi]
__device__ __forceinline__ void pswap(unsigned int& a, unsigned int& b) {
    asm volatile("v_permlane32_swap_b32 %0, %1" : "+v"(a), "+v"(b));
}
__device__ __forceinline__ void gll16(const void* g, void* l) {
    __builtin_amdgcn_global_load_lds(
        (const __attribute__((address_space(1))) unsigned int*)(g),
        (__attribute__((address_space(3))) unsigned int*)(l), 16, 0, 0);
}

// ws element offsets (unsigned short units) — sized, non-overlapping:
// Qo 2097152 | Kf 2097152 | Vf 2097152 | Wt 98304 | Em 16384  = 12.81 MB
#define OFF_Q  0u
#define OFF_K  2097152u
#define OFF_V  4194304u
#define OFF_W  6291456u
#define OFF_E  6389760u

// ---------------------------------------------------------------------------
// Kernel 0: W -> Wt (transposed, split bf16 hi/lo) + Em = exp2(mask*log2e) bf16
// grid (4,4,4), block 256.
// ---------------------------------------------------------------------------
__global__ __launch_bounds__(256) void wprep(
    const float* __restrict__ Wq, const float* __restrict__ Wk, const float* __restrict__ Wv,
    const float* __restrict__ maskg,
    unsigned short* __restrict__ Wt, unsigned short* __restrict__ Em)
{
    if (blockIdx.z == 3) {
        const int id16 = blockIdx.y * 4 + blockIdx.x;
        const int base = id16 * 1024 + threadIdx.x * 4;
        float4 m4 = *(const float4*)&maskg[base];
        ushort4 o;
        o.x = bf(__builtin_amdgcn_exp2f(m4.x * LOG2E));
        o.y = bf(__builtin_amdgcn_exp2f(m4.y * LOG2E));
        o.z = bf(__builtin_amdgcn_exp2f(m4.z * LOG2E));
        o.w = bf(__builtin_amdgcn_exp2f(m4.w * LOG2E));
        *(ushort4*)&Em[base] = o;
        return;
    }
    const float* W = (blockIdx.z == 0) ? Wq : (blockIdx.z == 1) ? Wk : Wv;
    unsigned short* Oh = Wt + (size_t)blockIdx.z * D_ * D_;
    unsigned short* Ol = Oh + 3 * D_ * D_;
    __shared__ float tf[32][36];
    const int t = threadIdx.x;
    const int kt = blockIdx.x * 32, ct = blockIdx.y * 32;
    {
        int kl = t >> 3, cl = (t & 7) * 4;
        float4 w4 = *(const float4*)&W[(size_t)(kt + kl) * D_ + ct + cl];
        tf[kl][cl + 0] = w4.x; tf[kl][cl + 1] = w4.y;
        tf[kl][cl + 2] = w4.z; tf[kl][cl + 3] = w4.w;
    }
    __syncthreads();
    {
        int cl = t >> 3, kl = (t & 7) * 4;
        ushort4 oh, ol;
        float v;
        v = tf[kl + 0][cl]; oh.x = bf(v); ol.x = bf(v - bf2f(oh.x));
        v = tf[kl + 1][cl]; oh.y = bf(v); ol.y = bf(v - bf2f(oh.y));
        v = tf[kl + 2][cl]; oh.z = bf(v); ol.z = bf(v - bf2f(oh.z));
        v = tf[kl + 3][cl]; oh.w = bf(v); ol.w = bf(v - bf2f(oh.w));
        *(ushort4*)&Oh[(size_t)(ct + cl) * D_ + kt + kl] = oh;
        *(ushort4*)&Ol[(size_t)(ct + cl) * D_ + kt + kl] = ol;
    }
}

// ---------------------------------------------------------------------------
// Kernel 1: QKV projection via split-bf16 MFMA (3 terms == fp32 accuracy).
// W fragments read DIRECTLY from global (L2-hot; removes 100MB of redundant
// per-block W staging traffic). X staged/split in LDS as before.
// Q out: [bh][s][32] bf16 (pre-scaled by scale*log2e).
// K out: Kf fragment-native: [bh][kb32][fr(2)][lane(64)][8]
// V out: Vf fragment-native, em-scaled: [bh][kb16][lane(64)][8]
// grid (BS/32, 2 c-halves, 3 modes), block 256 = 4 waves.
// ---------------------------------------------------------------------------
__global__ __launch_bounds__(256) void qkv_mfma(
    const float* __restrict__ Xq, const float* __restrict__ Xk, const float* __restrict__ Xv,
    const unsigned short* __restrict__ Wt, const float* __restrict__ maskg,
    const float* __restrict__ bq, const float* __restrict__ bk, const float* __restrict__ bv,
    unsigned short* __restrict__ Qo, unsigned short* __restrict__ Kf,
    unsigned short* __restrict__ Vf)
{
    const int mode = blockIdx.z, chalf = blockIdx.y;
    const float* X; const float* bias; float scl;
    if (mode == 0)      { X = Xq; bias = bq; scl = QSCALE; }
    else if (mode == 1) { X = Xk; bias = bk; scl = 1.f; }
    else                { X = Xv; bias = bv; scl = 1.f; }
    const unsigned short* WmH = Wt + (size_t)mode * D_ * D_;
    const unsigned short* WmL = WmH + 3 * D_ * D_;

    __shared__ __align__(16) unsigned short xa[2 * 32 * 136];   // X hi/lo; reused as bounce

    const int t = threadIdx.x;
    const long row0 = (long)blockIdx.x * 32;

    #pragma unroll
    for (int j = 0; j < 4; j++) {
        int idx = t + 256 * j;
        int r = idx >> 5, c4 = idx & 31;
        float4 v = *(const float4*)(X + (row0 + r) * D_ + c4 * 4);
        ushort4 ph, pl;
        ph.x = bf(v.x); pl.x = bf(v.x - bf2f(ph.x));
        ph.y = bf(v.y); pl.y = bf(v.y - bf2f(ph.y));
        ph.z = bf(v.z); pl.z = bf(v.z - bf2f(ph.z));
        ph.w = bf(v.w); pl.w = bf(v.w - bf2f(ph.w));
        *(ushort4*)&xa[r * 136 + c4 * 4] = ph;
        *(ushort4*)&xa[4352 + r * 136 + c4 * 4] = pl;
    }
    __syncthreads();

    const int w = t >> 6, lane = t & 63, lo = lane & 15, hi = lane >> 4;
    const int mf = w >> 1, nb = (w & 1) * 2;
    f32x4 acc[2] = {};
    #pragma unroll
    for (int kk = 0; kk < 4; kk++) {
        const int ko = kk * 32 + hi * 8;
        s16x8 ah = *(const s16x8*)&xa[(mf * 16 + lo) * 136 + ko];
        s16x8 al = *(const s16x8*)&xa[4352 + (mf * 16 + lo) * 136 + ko];
        #pragma unroll
        for (int n2 = 0; n2 < 2; n2++) {
            const int nf = nb + n2;
            const size_t wrow = (size_t)(chalf * 64 + nf * 16 + lo) * D_ + ko;
            s16x8 bh2 = *(const s16x8*)&WmH[wrow];    // global, L2-hot
            s16x8 bl2 = *(const s16x8*)&WmL[wrow];
            acc[n2] = __builtin_amdgcn_mfma_f32_16x16x32_bf16(ah, bh2, acc[n2], 0, 0, 0);
            acc[n2] = __builtin_amdgcn_mfma_f32_16x16x32_bf16(al, bh2, acc[n2], 0, 0, 0);
            acc[n2] = __builtin_amdgcn_mfma_f32_16x16x32_bf16(ah, bl2, acc[n2], 0, 0, 0);
        }
    }
    __syncthreads();   // xa free for bounce

    const long b_i = row0 >> 11;
    const long s0g = row0 & 2047;

    if (mode < 2) {
        #pragma unroll
        for (int n2 = 0; n2 < 2; n2++) {
            int c_l = (nb + n2) * 16 + lo;
            float bb = bias[chalf * 64 + c_l];
            #pragma unroll
            for (int r = 0; r < 4; r++) {
                int s = mf * 16 + hi * 4 + r;
                xa[s * 72 + c_l] = bf((acc[n2][r] + bb) * scl);
            }
        }
        __syncthreads();
        int s = t >> 3, part = t & 7;
        int c_g = chalf * 64 + part * 8;
        int h = c_g >> 5, dd = c_g & 31;
        long s_i = s0g + s;
        int bh = (int)(b_i * H_ + h);
        uint4 val = *(const uint4*)&xa[s * 72 + part * 8];
        if (mode == 0) {
            *(uint4*)(Qo + ((size_t)bh * S_ + s_i) * DH_ + dd) = val;
        } else {
            int fr = dd >> 4, hwd = (dd >> 3) & 1;
            size_t off = ((((size_t)bh * 64 + (s_i >> 5)) * 2 + fr) * 64
                          + (s_i & 31) + hwd * 32) * 8;
            *(uint4*)(Kf + off) = val;
        }
    } else {
        float emr[4];
        #pragma unroll
        for (int r = 0; r < 4; r++) {
            const int s_l = mf * 16 + hi * 4 + r;
            emr[r] = __builtin_amdgcn_exp2f(maskg[b_i * S_ + s0g + s_l] * LOG2E);
        }
        #pragma unroll
        for (int n2 = 0; n2 < 2; n2++) {
            int c_l = (nb + n2) * 16 + lo;
            float bb = bias[chalf * 64 + c_l];
            #pragma unroll
            for (int r = 0; r < 4; r++) {
                int s = mf * 16 + hi * 4 + r;
                xa[c_l * 68 + s] = bf((acc[n2][r] + bb) * emr[r]);
            }
        }
        __syncthreads();
        if (t < 128) {
            int c_l = t >> 1, sh2 = (t & 1) * 16;
            int c_g = chalf * 64 + c_l;
            int h = c_g >> 5, dd = c_g & 31;
            long key0 = s0g + sh2;
            int bh = (int)(b_i * H_ + h);
            size_t base = (((size_t)bh * 128 + (key0 >> 4)) * 64 + dd) * 8;
            uint2 p0 = *(const uint2*)&xa[c_l * 68 + sh2 + 0];
            uint2 p1 = *(const uint2*)&xa[c_l * 68 + sh2 + 4];
            uint2 p2 = *(const uint2*)&xa[c_l * 68 + sh2 + 8];
            uint2 p3 = *(const uint2*)&xa[c_l * 68 + sh2 + 12];
            *(uint4*)(Vf + base)       = make_uint4(p0.x, p0.y, p1.x, p1.y);  // keys 0-7 (hw=0)
            *(uint4*)(Vf + base + 256) = make_uint4(p2.x, p2.y, p3.x, p3.y);  // keys 8-15 (hw=1)
        }
    }
}

// ---------------------------------------------------------------------------
// Kernel 2: flash attention, 32x32x16 MFMA, WAVE-PRIVATE LDS staging,
// ZERO in-loop barriers. r12/r13's per-tile block-wide s_barrier convoyed
// 8 waves (arrive->burst->idle, 16x) and was only needed because staging was
// block-shared — a sharing that r9 proved buys nothing. Now: each wave glls
// its OWN K/V quarter (4 glls/tile, 2 bufs, depth 2) into a private 8KB LDS
// region; per-tile sync is s_waitcnt vmcnt(4) on its own loads (covered by
// 2 tiles of compute) + lgkmcnt(0) before re-staging a buffer (WAR). Waves
// free-run and self-stagger. Em block-shared read-only (one prologue
// barrier). LDS 68KB -> 2 blocks/CU. Merge aliases staging LDS at the end.
// grid 1024 (32 bh x 32 q-tiles of 64 q; 4 bh per XCD), block 512 = 8 waves:
// wave = (q-half: w>>2, key-quarter: w&3).
// ---------------------------------------------------------------------------
__global__ __launch_bounds__(512) void flash_mfma(
    const unsigned short* __restrict__ Qg, const unsigned short* __restrict__ Kfg,
    const unsigned short* __restrict__ Vfg, const unsigned short* __restrict__ Emg,
    const float* __restrict__ head_mask, float* __restrict__ Out)
{
    // shorts: [8 waves][2 bufs][2048] staging = 32768 | em @32768 (2048) = 69632 B
    __shared__ __align__(16) unsigned short smem[34816];

    const int t = threadIdx.x, w = t >> 6, lane = t & 63;
    const int l31 = lane & 31, hw = lane >> 5;
    const int kq = w & 3, qh = w >> 2;

    const int lid = blockIdx.x;
    const int xcd = lid & 7, ser = lid >> 3;          // blocks round-robin XCDs
    const int bh = xcd * 4 + (ser >> 5);              // 4 bh per XCD (32 total)
    const int qi = ser & 31;
    const int b = bh >> 2, h = bh & 3;
    const int q0 = qi * 64 + qh * 32;

    // Q B-fragments
    const unsigned short* qp = Qg + ((size_t)bh * S_ + q0 + l31) * DH_ + hw * 8;
    const s16x8 qf0 = *(const s16x8*)qp;
    const s16x8 qf1 = *(const s16x8*)(qp + 16);

    // em: stage full row for batch b (2048 bf16 = 4KB) into LDS once
    *(uint2*)&smem[32768 + t * 4] = *(const uint2*)(Emg + (size_t)b * S_ + t * 4);

    // wave-private staging: source = this wave's kq quarter of each 128-key tile
    const size_t kvbase = (size_t)bh * 65536;
    const unsigned short* ksrc = Kfg + kvbase + (size_t)kq * 1024 + (size_t)lane * 8;
    const unsigned short* vsrc = Vfg + kvbase + (size_t)kq * 1024 + (size_t)lane * 8;
    unsigned short* reg0 = &smem[w * 4096];          // buf0: K[0..1023] V[1024..2047]
    unsigned short* reg1 = &smem[w * 4096 + 2048];   // buf1

    // prologue: stage tiles 0,1 (8 glls outstanding)
    {
        gll16(ksrc,              reg0);
        gll16(ksrc + 512,        reg0 + 512);
        gll16(vsrc,              reg0 + 1024);
        gll16(vsrc + 512,        reg0 + 1536);
        gll16(ksrc + 4096,       reg1);
        gll16(ksrc + 4096 + 512, reg1 + 512);
        gll16(vsrc + 4096,       reg1 + 1024);
        gll16(vsrc + 4096 + 512, reg1 + 1536);
    }
    __syncthreads();   // em visibility (one-time; drains prologue glls too)

    f32x16 ctx = {}, lacc = {};
    const f32x16 z16 = {};

    for (int tile = 0; tile < 16; tile++) {
        unsigned short* cur = (tile & 1) ? reg1 : reg0;

        // counted wait on OWN loads: current tile done, next tile in flight
        if (tile < 15) { asm volatile("s_waitcnt vmcnt(4)" ::: "memory"); }
        else           { asm volatile("s_waitcnt vmcnt(0)" ::: "memory"); }
        __builtin_amdgcn_sched_barrier(0);

        const s16x8 kf0 = *(const s16x8*)(cur + (size_t)lane * 8);
        const s16x8 kf1 = *(const s16x8*)(cur + 512 + (size_t)lane * 8);
        const s16x8 vf0 = *(const s16x8*)(cur + 1024 + (size_t)lane * 8);
        const s16x8 vf1 = *(const s16x8*)(cur + 1536 + (size_t)lane * 8);
        const s16x8 ef0 = *(const s16x8*)&smem[32768 + tile * 128 + kq * 32 + hw * 8];
        const s16x8 ef1 = *(const s16x8*)&smem[32768 + tile * 128 + kq * 32 + hw * 8 + 16];

        // drain ds_reads into VGPRs, then re-stage this buffer for tile+2 (WAR-safe)
        asm volatile("s_waitcnt lgkmcnt(0)" ::: "memory");
        __builtin_amdgcn_sched_barrier(0);
        if (tile < 14) {
            const unsigned short* kp2 = ksrc + (size_t)(tile + 2) * 4096;
            const unsigned short* vp2 = vsrc + (size_t)(tile + 2) * 4096;
            gll16(kp2,       cur);
            gll16(kp2 + 512, cur + 512);
            gll16(vp2,       cur + 1024);
            gll16(vp2 + 512, cur + 1536);
        }

        // ---- QK^T (swapped): S^T[key][q], exp2 domain
        __builtin_amdgcn_s_setprio(1);
        f32x16 s = __builtin_amdgcn_mfma_f32_32x32x16_bf16(kf0, qf0, z16, 0, 0, 0);
        s = __builtin_amdgcn_mfma_f32_32x32x16_bf16(kf1, qf1, s, 0, 0, 0);
        __builtin_amdgcn_s_setprio(0);

        // ---- P = exp2(s), pack (1 cvt_pk each), permlane into PV A-frags
        unsigned int pd[8];
        #pragma unroll
        for (int j = 0; j < 8; j++) {
            const float p0 = __builtin_amdgcn_exp2f(s[2 * j]);
            const float p1 = __builtin_amdgcn_exp2f(s[2 * j + 1]);
            pd[j] = pk2(p0, p1);
        }
        pswap(pd[0], pd[2]); pswap(pd[1], pd[3]);
        pswap(pd[4], pd[6]); pswap(pd[5], pd[7]);
        const s16x8 pa0 = __builtin_bit_cast(s16x8, make_uint4(pd[0], pd[1], pd[2], pd[3]));
        const s16x8 pa1 = __builtin_bit_cast(s16x8, make_uint4(pd[4], pd[5], pd[6], pd[7]));

        // ---- PV + l
        __builtin_amdgcn_s_setprio(1);
        ctx  = __builtin_amdgcn_mfma_f32_32x32x16_bf16(pa0, vf0, ctx, 0, 0, 0);
        lacc = __builtin_amdgcn_mfma_f32_32x32x16_bf16(pa0, ef0, lacc, 0, 0, 0);
        ctx  = __builtin_amdgcn_mfma_f32_32x32x16_bf16(pa1, vf1, ctx, 0, 0, 0);
        lacc = __builtin_amdgcn_mfma_f32_32x32x16_bf16(pa1, ef1, lacc, 0, 0, 0);
        __builtin_amdgcn_s_setprio(0);
    }

    // ---- merge: alias smem as float scratch (full drain + barrier first)
    __syncthreads();
    float* ms = (float*)smem;   // [2][2][64][33] floats = 33792 B < 69632 B
    #define MS(qh_, sl_, ln_, r_) ms[(((qh_) * 2 + (sl_)) * 64 + (ln_)) * 33 + (r_)]

    if (kq >= 2) {
        #pragma unroll
        for (int r = 0; r < 16; r++) {
            MS(qh, kq - 2, lane, r) = ctx[r];
            MS(qh, kq - 2, lane, 16 + r) = lacc[r];
        }
    }
    __syncthreads();
    if (kq < 2) {
        #pragma unroll
        for (int r = 0; r < 16; r++) {
            ctx[r]  += MS(qh, kq, lane, r);
            lacc[r] += MS(qh, kq, lane, 16 + r);
        }
    }
    __syncthreads();
    if (kq == 1) {
        #pragma unroll
        for (int r = 0; r < 16; r++) {
            MS(qh, 0, lane, r) = ctx[r];
            MS(qh, 0, lane, 16 + r) = lacc[r];
        }
    }
    __syncthreads();
    if (kq == 0) {
        #pragma unroll
        for (int r = 0; r < 16; r++) {
            ctx[r]  += MS(qh, 0, lane, r);
            lacc[r] += MS(qh, 0, lane, 16 + r);
        }
        const float hm = head_mask[h];
        #pragma unroll
        for (int r = 0; r < 16; r++) {
            const int qrow = (r & 3) + 8 * (r >> 2) + 4 * hw;
            Out[((size_t)b * S_ + q0 + qrow) * D_ + h * DH_ + l31] = ctx[r] * hm / lacc[r];
        }
    }
    #undef MS
}

// ---------------------------------------------------------------------------
extern "C" void kernel_launch(void* const* d_in, const int* in_sizes, int n_in,
                              void* d_out, int out_size, void* d_ws, size_t ws_size,
                              hipStream_t stream) {
    const float* Xq   = (const float*)d_in[0];
    const float* Xk   = (const float*)d_in[1];
    const float* Xv   = (const float*)d_in[2];
    const float* mask = (const float*)d_in[3];
    const float* hm   = (const float*)d_in[4];
    const float* Wq   = (const float*)d_in[5];
    const float* bq   = (const float*)d_in[6];
    const float* Wk   = (const float*)d_in[7];
    const float* bk   = (const float*)d_in[8];
    const float* Wv   = (const float*)d_in[9];
    const float* bv   = (const float*)d_in[10];
    float* out = (float*)d_out;

    unsigned short* ws = (unsigned short*)d_ws;
    unsigned short* Qo = ws + OFF_Q;    // [bh][s][32] bf16
    unsigned short* Kf = ws + OFF_K;    // frag-native K
    unsigned short* Vf = ws + OFF_V;    // frag-native V (em-scaled)
    unsigned short* Wt = ws + OFF_W;    // [2][3][128][128] split bf16
    unsigned short* Em = ws + OFF_E;    // [b][s] bf16 exp(mask)

    wprep<<<dim3(4, 4, 4), 256, 0, stream>>>(Wq, Wk, Wv, mask, Wt, Em);
    qkv_mfma<<<dim3(BS_ / 32, 2, 3), 256, 0, stream>>>(Xq, Xk, Xv, Wt, mask,
                                                       bq, bk, bv, Qo, Kf, Vf);
    flash_mfma<<<dim3(1024), 512, 0, stream>>>(Qo, Kf, Vf, Em, hm, out);
}

// Round 15
// 54.128 us; speedup vs baseline: 1.3550x; 1.3550x over previous
//
#include <hip/hip_runtime.h>
#include <hip/hip_bf16.h>
#include <math.h>

#define B_ 8
#define S_ 2048
#define H_ 4
#define DH_ 32
#define D_ 128
#define BS_ (B_ * S_)
#define LOG2E 1.4426950408889634f
#define QSCALE (0.17677669529663687f * LOG2E)

typedef float f32x4  __attribute__((ext_vector_type(4)));
typedef float f32x16 __attribute__((ext_vector_type(16)));
typedef short s16x8  __attribute__((ext_vector_type(8)));

__device__ __forceinline__ unsigned short bf(float x) {
    return __builtin_bit_cast(unsigned short, __float2bfloat16(x));
}
__device__ __forceinline__ float bf2f(unsigned short u) {
    return __builtin_bit_cast(float, (unsigned int)u << 16);
}
// v_cvt_pk_bf16_f32: dst.lo = bf16(a), dst.hi = bf16(b)  (1 VALU instr)
__device__ __forceinline__ unsigned int pk2(float a, float b) {
    unsigned int r;
    asm("v_cvt_pk_bf16_f32 %0, %1, %2" : "=v"(r) : "v"(a), "v"(b));
    return r;
}
// v_permlane32_swap_b32: a' = [a_lo | b_lo], b' = [a_hi | b_hi]
__device__ __forceinline__ void pswap(unsigned int& a, unsigned int& b) {
    asm volatile("v_permlane32_swap_b32 %0, %1" : "+v"(a), "+v"(b));
}
__device__ __forceinline__ void gll16(const void* g, void* l) {
    __builtin_amdgcn_global_load_lds(
        (const __attribute__((address_space(1))) unsigned int*)(g),
        (__attribute__((address_space(3))) unsigned int*)(l), 16, 0, 0);
}

// ws element offsets (unsigned short units) — sized, non-overlapping:
// Qo 2097152 | Kf 2097152 | Vf 2097152 | Wt 98304 | Em 16384  = 12.81 MB
#define OFF_Q  0u
#define OFF_K  2097152u
#define OFF_V  4194304u
#define OFF_W  6291456u
#define OFF_E  6389760u

// ---------------------------------------------------------------------------
// Kernel 0: W -> Wt (transposed, split bf16 hi/lo) + Em = exp2(mask*log2e) bf16
// grid (4,4,4), block 256.
// ---------------------------------------------------------------------------
__global__ __launch_bounds__(256) void wprep(
    const float* __restrict__ Wq, const float* __restrict__ Wk, const float* __restrict__ Wv,
    const float* __restrict__ maskg,
    unsigned short* __restrict__ Wt, unsigned short* __restrict__ Em)
{
    if (blockIdx.z == 3) {
        const int id16 = blockIdx.y * 4 + blockIdx.x;
        const int base = id16 * 1024 + threadIdx.x * 4;
        float4 m4 = *(const float4*)&maskg[base];
        ushort4 o;
        o.x = bf(__builtin_amdgcn_exp2f(m4.x * LOG2E));
        o.y = bf(__builtin_amdgcn_exp2f(m4.y * LOG2E));
        o.z = bf(__builtin_amdgcn_exp2f(m4.z * LOG2E));
        o.w = bf(__builtin_amdgcn_exp2f(m4.w * LOG2E));
        *(ushort4*)&Em[base] = o;
        return;
    }
    const float* W = (blockIdx.z == 0) ? Wq : (blockIdx.z == 1) ? Wk : Wv;
    unsigned short* Oh = Wt + (size_t)blockIdx.z * D_ * D_;
    unsigned short* Ol = Oh + 3 * D_ * D_;
    __shared__ float tf[32][36];
    const int t = threadIdx.x;
    const int kt = blockIdx.x * 32, ct = blockIdx.y * 32;
    {
        int kl = t >> 3, cl = (t & 7) * 4;
        float4 w4 = *(const float4*)&W[(size_t)(kt + kl) * D_ + ct + cl];
        tf[kl][cl + 0] = w4.x; tf[kl][cl + 1] = w4.y;
        tf[kl][cl + 2] = w4.z; tf[kl][cl + 3] = w4.w;
    }
    __syncthreads();
    {
        int cl = t >> 3, kl = (t & 7) * 4;
        ushort4 oh, ol;
        float v;
        v = tf[kl + 0][cl]; oh.x = bf(v); ol.x = bf(v - bf2f(oh.x));
        v = tf[kl + 1][cl]; oh.y = bf(v); ol.y = bf(v - bf2f(oh.y));
        v = tf[kl + 2][cl]; oh.z = bf(v); ol.z = bf(v - bf2f(oh.z));
        v = tf[kl + 3][cl]; oh.w = bf(v); ol.w = bf(v - bf2f(oh.w));
        *(ushort4*)&Oh[(size_t)(ct + cl) * D_ + kt + kl] = oh;
        *(ushort4*)&Ol[(size_t)(ct + cl) * D_ + kt + kl] = ol;
    }
}

// ---------------------------------------------------------------------------
// Kernel 1: QKV projection via split-bf16 MFMA (3 terms == fp32 accuracy).
// (r13 version: W staged in LDS — r14's direct-global W regressed 2x.)
// Q out: [bh][s][32] bf16 (pre-scaled by scale*log2e).
// K out: Kf fragment-native: [bh][kb32][fr(2)][lane(64)][8]
// V out: Vf fragment-native, em-scaled: [bh][kb16][lane(64)][8]
// grid (BS/32, 2 c-halves, 3 modes), block 256 = 4 waves.
// ---------------------------------------------------------------------------
__global__ __launch_bounds__(256) void qkv_mfma(
    const float* __restrict__ Xq, const float* __restrict__ Xk, const float* __restrict__ Xv,
    const unsigned short* __restrict__ Wt, const float* __restrict__ maskg,
    const float* __restrict__ bq, const float* __restrict__ bk, const float* __restrict__ bv,
    unsigned short* __restrict__ Qo, unsigned short* __restrict__ Kf,
    unsigned short* __restrict__ Vf)
{
    const int mode = blockIdx.z, chalf = blockIdx.y;
    const float* X; const float* bias; float scl;
    if (mode == 0)      { X = Xq; bias = bq; scl = QSCALE; }
    else if (mode == 1) { X = Xk; bias = bk; scl = 1.f; }
    else                { X = Xv; bias = bv; scl = 1.f; }
    const unsigned short* WmH = Wt + (size_t)mode * D_ * D_;
    const unsigned short* WmL = WmH + 3 * D_ * D_;

    __shared__ __align__(16) unsigned short xa[2 * 32 * 136];   // X hi/lo; reused as bounce
    __shared__ __align__(16) unsigned short wt[2 * 64 * 136];   // Wt hi/lo, 64 c-rows

    const int t = threadIdx.x;
    const long row0 = (long)blockIdx.x * 32;

    #pragma unroll
    for (int j = 0; j < 8; j++) {
        int idx = t + 256 * j;
        int part = idx >> 10, i2 = idx & 1023;
        int r = i2 >> 4, c16 = i2 & 15;
        const unsigned short* src = part ? WmL : WmH;
        uint4 v = *(const uint4*)&src[(size_t)(chalf * 64 + r) * D_ + c16 * 8];
        *(uint4*)&wt[part * 8704 + r * 136 + c16 * 8] = v;
    }
    #pragma unroll
    for (int j = 0; j < 4; j++) {
        int idx = t + 256 * j;
        int r = idx >> 5, c4 = idx & 31;
        float4 v = *(const float4*)(X + (row0 + r) * D_ + c4 * 4);
        ushort4 ph, pl;
        ph.x = bf(v.x); pl.x = bf(v.x - bf2f(ph.x));
        ph.y = bf(v.y); pl.y = bf(v.y - bf2f(ph.y));
        ph.z = bf(v.z); pl.z = bf(v.z - bf2f(ph.z));
        ph.w = bf(v.w); pl.w = bf(v.w - bf2f(ph.w));
        *(ushort4*)&xa[r * 136 + c4 * 4] = ph;
        *(ushort4*)&xa[4352 + r * 136 + c4 * 4] = pl;
    }
    __syncthreads();

    const int w = t >> 6, lane = t & 63, lo = lane & 15, hi = lane >> 4;
    const int mf = w >> 1, nb = (w & 1) * 2;
    f32x4 acc[2] = {};
    #pragma unroll
    for (int kk = 0; kk < 4; kk++) {
        const int ko = kk * 32 + hi * 8;
        s16x8 ah = *(const s16x8*)&xa[(mf * 16 + lo) * 136 + ko];
        s16x8 al = *(const s16x8*)&xa[4352 + (mf * 16 + lo) * 136 + ko];
        #pragma unroll
        for (int n2 = 0; n2 < 2; n2++) {
            const int nf = nb + n2;
            s16x8 bh2 = *(const s16x8*)&wt[(nf * 16 + lo) * 136 + ko];
            s16x8 bl2 = *(const s16x8*)&wt[8704 + (nf * 16 + lo) * 136 + ko];
            acc[n2] = __builtin_amdgcn_mfma_f32_16x16x32_bf16(ah, bh2, acc[n2], 0, 0, 0);
            acc[n2] = __builtin_amdgcn_mfma_f32_16x16x32_bf16(al, bh2, acc[n2], 0, 0, 0);
            acc[n2] = __builtin_amdgcn_mfma_f32_16x16x32_bf16(ah, bl2, acc[n2], 0, 0, 0);
        }
    }
    __syncthreads();   // xa free for bounce

    const long b_i = row0 >> 11;
    const long s0g = row0 & 2047;

    if (mode < 2) {
        #pragma unroll
        for (int n2 = 0; n2 < 2; n2++) {
            int c_l = (nb + n2) * 16 + lo;
            float bb = bias[chalf * 64 + c_l];
            #pragma unroll
            for (int r = 0; r < 4; r++) {
                int s = mf * 16 + hi * 4 + r;
                xa[s * 72 + c_l] = bf((acc[n2][r] + bb) * scl);
            }
        }
        __syncthreads();
        int s = t >> 3, part = t & 7;
        int c_g = chalf * 64 + part * 8;
        int h = c_g >> 5, dd = c_g & 31;
        long s_i = s0g + s;
        int bh = (int)(b_i * H_ + h);
        uint4 val = *(const uint4*)&xa[s * 72 + part * 8];
        if (mode == 0) {
            *(uint4*)(Qo + ((size_t)bh * S_ + s_i) * DH_ + dd) = val;
        } else {
            int fr = dd >> 4, hwd = (dd >> 3) & 1;
            size_t off = ((((size_t)bh * 64 + (s_i >> 5)) * 2 + fr) * 64
                          + (s_i & 31) + hwd * 32) * 8;
            *(uint4*)(Kf + off) = val;
        }
    } else {
        float emr[4];
        #pragma unroll
        for (int r = 0; r < 4; r++) {
            const int s_l = mf * 16 + hi * 4 + r;
            emr[r] = __builtin_amdgcn_exp2f(maskg[b_i * S_ + s0g + s_l] * LOG2E);
        }
        #pragma unroll
        for (int n2 = 0; n2 < 2; n2++) {
            int c_l = (nb + n2) * 16 + lo;
            float bb = bias[chalf * 64 + c_l];
            #pragma unroll
            for (int r = 0; r < 4; r++) {
                int s = mf * 16 + hi * 4 + r;
                xa[c_l * 68 + s] = bf((acc[n2][r] + bb) * emr[r]);
            }
        }
        __syncthreads();
        if (t < 128) {
            int c_l = t >> 1, sh2 = (t & 1) * 16;
            int c_g = chalf * 64 + c_l;
            int h = c_g >> 5, dd = c_g & 31;
            long key0 = s0g + sh2;
            int bh = (int)(b_i * H_ + h);
            size_t base = (((size_t)bh * 128 + (key0 >> 4)) * 64 + dd) * 8;
            uint2 p0 = *(const uint2*)&xa[c_l * 68 + sh2 + 0];
            uint2 p1 = *(const uint2*)&xa[c_l * 68 + sh2 + 4];
            uint2 p2 = *(const uint2*)&xa[c_l * 68 + sh2 + 8];
            uint2 p3 = *(const uint2*)&xa[c_l * 68 + sh2 + 12];
            *(uint4*)(Vf + base)       = make_uint4(p0.x, p0.y, p1.x, p1.y);  // keys 0-7 (hw=0)
            *(uint4*)(Vf + base + 256) = make_uint4(p2.x, p2.y, p3.x, p3.y);  // keys 8-15 (hw=1)
        }
    }
}

// ---------------------------------------------------------------------------
// Kernel 2: flash attention, 32x32x16 MFMA, SOFTWARE-PIPELINED (T15):
// per iteration, QK^T for tile n+1 is issued on the matrix pipe BEFORE the
// exp2/pack block of tile n runs on the VALU/trans pipe — breaking the
// serial ds_read->QK->exp2->PV chain that pinned r8-r14 at ~40us (the r14
// null killed the convoy theory; what all variants shared was zero
// cross-tile ILP, enforced by my own waitcnt fences). Staging = r13's
// block-shared 3-buf counted-vmcnt scheme, shifted one tile earlier:
// prologue stages tiles 0,1,2; iter n waits vmcnt(2) == tile n+1 ready
// (tile n+2 in flight), barrier, ds_read tile n+1 + QK(n+1), gll(n+3)
// into buf n%3 (WAR-safe: tile n's reads completed in iter n-1), then
// exp2/PV for tile n from registers. V/em for tile n held from iter n-1.
// grid 1024 (32 bh x 32 q-tiles of 64 q; 4 bh per XCD), block 512 = 8 waves:
// wave = (q-half: w>>2, key-quarter: w&3). LDS 52KB.
// ---------------------------------------------------------------------------
__global__ __launch_bounds__(512) void flash_mfma(
    const unsigned short* __restrict__ Qg, const unsigned short* __restrict__ Kfg,
    const unsigned short* __restrict__ Vfg, const unsigned short* __restrict__ Emg,
    const float* __restrict__ head_mask, float* __restrict__ Out)
{
    // shorts: K bufs [3][4096] @0 | V bufs [3][4096] @12288 | em @24576
    __shared__ __align__(16) unsigned short smem[26624];   // 53248 B

    const int t = threadIdx.x, w = t >> 6, lane = t & 63;
    const int l31 = lane & 31, hw = lane >> 5;
    const int kq = w & 3, qh = w >> 2;

    const int lid = blockIdx.x;
    const int xcd = lid & 7, ser = lid >> 3;          // blocks round-robin XCDs
    const int bh = xcd * 4 + (ser >> 5);              // 4 bh per XCD (32 total)
    const int qi = ser & 31;
    const int b = bh >> 2, h = bh & 3;
    const int q0 = qi * 64 + qh * 32;

    // em: stage full row for batch b (2048 bf16 = 4KB) into LDS once
    *(uint2*)&smem[24576 + t * 4] = *(const uint2*)(Emg + (size_t)b * S_ + t * 4);

    // Q B-fragments
    const unsigned short* qp = Qg + ((size_t)bh * S_ + q0 + l31) * DH_ + hw * 8;
    const s16x8 qf0 = *(const s16x8*)qp;
    const s16x8 qf1 = *(const s16x8*)(qp + 16);

    // staging sources: wave w stages chunk w (512 shorts = 1KB) of each tile
    const size_t kvbase = (size_t)bh * 65536;
    const unsigned short* ksrc = Kfg + kvbase + (size_t)w * 512 + (size_t)lane * 8;
    const unsigned short* vsrc = Vfg + kvbase + (size_t)w * 512 + (size_t)lane * 8;

    // prologue: stage tiles 0,1,2 into bufs 0,1,2
    #pragma unroll
    for (int p = 0; p < 3; p++) {
        gll16(ksrc + (size_t)p * 4096, &smem[p * 4096 + w * 512]);
        gll16(vsrc + (size_t)p * 4096, &smem[12288 + p * 4096 + w * 512]);
    }
    __syncthreads();   // full drain: tiles 0-2 resident + em visible

    const unsigned short* emb = &smem[24576];
    f32x16 ctx = {}, lacc = {};
    const f32x16 z16 = {};

    // prime: tile 0 fragments + QK(0)
    s16x8 vf_cur0, vf_cur1, ef_cur0, ef_cur1;
    f32x16 s_cur;
    {
        const unsigned short* kb = &smem[kq * 1024];
        const unsigned short* vb = &smem[12288 + kq * 1024];
        s16x8 k0 = *(const s16x8*)(kb + (size_t)lane * 8);
        s16x8 k1 = *(const s16x8*)(kb + 512 + (size_t)lane * 8);
        vf_cur0 = *(const s16x8*)(vb + (size_t)lane * 8);
        vf_cur1 = *(const s16x8*)(vb + 512 + (size_t)lane * 8);
        ef_cur0 = *(const s16x8*)(emb + kq * 32 + hw * 8);
        ef_cur1 = *(const s16x8*)(emb + kq * 32 + hw * 8 + 16);
        s_cur = __builtin_amdgcn_mfma_f32_32x32x16_bf16(k0, qf0, z16, 0, 0, 0);
        s_cur = __builtin_amdgcn_mfma_f32_32x32x16_bf16(k1, qf1, s_cur, 0, 0, 0);
    }

    #pragma unroll
    for (int tile = 0; tile < 16; tile++) {
        // counted wait: tile n+1's glls done; tile n+2's stay in flight
        if (tile < 14)       { asm volatile("s_waitcnt vmcnt(2)" ::: "memory"); }
        else if (tile == 14) { asm volatile("s_waitcnt vmcnt(0)" ::: "memory"); }
        __builtin_amdgcn_sched_barrier(0);
        __builtin_amdgcn_s_barrier();
        __builtin_amdgcn_sched_barrier(0);

        f32x16 s_next;
        s16x8 vf_n0, vf_n1, ef_n0, ef_n1;
        if (tile < 15) {
            // ds_read tile n+1 fragments; QK(n+1) issues on the matrix pipe
            // and runs UNDER the exp2 block below (the pipeline win)
            const int nb3 = ((tile + 1) % 3) * 4096 + kq * 1024;
            const unsigned short* kb = &smem[nb3];
            const unsigned short* vb = &smem[12288 + nb3];
            s16x8 kn0 = *(const s16x8*)(kb + (size_t)lane * 8);
            s16x8 kn1 = *(const s16x8*)(kb + 512 + (size_t)lane * 8);
            vf_n0 = *(const s16x8*)(vb + (size_t)lane * 8);
            vf_n1 = *(const s16x8*)(vb + 512 + (size_t)lane * 8);
            ef_n0 = *(const s16x8*)(emb + (tile + 1) * 128 + kq * 32 + hw * 8);
            ef_n1 = *(const s16x8*)(emb + (tile + 1) * 128 + kq * 32 + hw * 8 + 16);
            s_next = __builtin_amdgcn_mfma_f32_32x32x16_bf16(kn0, qf0, z16, 0, 0, 0);
            s_next = __builtin_amdgcn_mfma_f32_32x32x16_bf16(kn1, qf1, s_next, 0, 0, 0);

            // re-stage buf n%3 for tile n+3 (WAR-safe: tile n's ds_reads
            // completed before QK(n) issued, which was last iteration)
            if (tile <= 12) {
                gll16(ksrc + (size_t)(tile + 3) * 4096, &smem[(tile % 3) * 4096 + w * 512]);
                gll16(vsrc + (size_t)(tile + 3) * 4096, &smem[12288 + (tile % 3) * 4096 + w * 512]);
            }
        }

        // ---- exp2/pack/permlane on s_cur (trans/VALU; overlaps QK(n+1))
        unsigned int pd[8];
        #pragma unroll
        for (int j = 0; j < 8; j++) {
            pd[j] = pk2(__builtin_amdgcn_exp2f(s_cur[2 * j]),
                        __builtin_amdgcn_exp2f(s_cur[2 * j + 1]));
        }
        pswap(pd[0], pd[2]); pswap(pd[1], pd[3]);
        pswap(pd[4], pd[6]); pswap(pd[5], pd[7]);
        const s16x8 pa0 = __builtin_bit_cast(s16x8, make_uint4(pd[0], pd[1], pd[2], pd[3]));
        const s16x8 pa1 = __builtin_bit_cast(s16x8, make_uint4(pd[4], pd[5], pd[6], pd[7]));

        // ---- PV + l for tile n (V/em held in registers since iter n-1)
        ctx  = __builtin_amdgcn_mfma_f32_32x32x16_bf16(pa0, vf_cur0, ctx, 0, 0, 0);
        lacc = __builtin_amdgcn_mfma_f32_32x32x16_bf16(pa0, ef_cur0, lacc, 0, 0, 0);
        ctx  = __builtin_amdgcn_mfma_f32_32x32x16_bf16(pa1, vf_cur1, ctx, 0, 0, 0);
        lacc = __builtin_amdgcn_mfma_f32_32x32x16_bf16(pa1, ef_cur1, lacc, 0, 0, 0);

        if (tile < 15) {
            s_cur = s_next;
            vf_cur0 = vf_n0; vf_cur1 = vf_n1;
            ef_cur0 = ef_n0; ef_cur1 = ef_n1;
        }
    }

    // ---- merge: alias smem as float scratch (full drain + barrier first)
    __syncthreads();
    float* ms = (float*)smem;   // [2][2][64][33] floats = 33792 B < 53248 B
    #define MS(qh_, sl_, ln_, r_) ms[(((qh_) * 2 + (sl_)) * 64 + (ln_)) * 33 + (r_)]

    if (kq >= 2) {
        #pragma unroll
        for (int r = 0; r < 16; r++) {
            MS(qh, kq - 2, lane, r) = ctx[r];
            MS(qh, kq - 2, lane, 16 + r) = lacc[r];
        }
    }
    __syncthreads();
    if (kq < 2) {
        #pragma unroll
        for (int r = 0; r < 16; r++) {
            ctx[r]  += MS(qh, kq, lane, r);
            lacc[r] += MS(qh, kq, lane, 16 + r);
        }
    }
    __syncthreads();
    if (kq == 1) {
        #pragma unroll
        for (int r = 0; r < 16; r++) {
            MS(qh, 0, lane, r) = ctx[r];
            MS(qh, 0, lane, 16 + r) = lacc[r];
        }
    }
    __syncthreads();
    if (kq == 0) {
        #pragma unroll
        for (int r = 0; r < 16; r++) {
            ctx[r]  += MS(qh, 0, lane, r);
            lacc[r] += MS(qh, 0, lane, 16 + r);
        }
        const float hm = head_mask[h];
        #pragma unroll
        for (int r = 0; r < 16; r++) {
            const int qrow = (r & 3) + 8 * (r >> 2) + 4 * hw;
            Out[((size_t)b * S_ + q0 + qrow) * D_ + h * DH_ + l31] = ctx[r] * hm / lacc[r];
        }
    }
    #undef MS
}

// ---------------------------------------------------------------------------
extern "C" void kernel_launch(void* const* d_in, const int* in_sizes, int n_in,
                              void* d_out, int out_size, void* d_ws, size_t ws_size,
                              hipStream_t stream) {
    const float* Xq   = (const float*)d_in[0];
    const float* Xk   = (const float*)d_in[1];
    const float* Xv   = (const float*)d_in[2];
    const float* mask = (const float*)d_in[3];
    const float* hm   = (const float*)d_in[4];
    const float* Wq   = (const float*)d_in[5];
    const float* bq   = (const float*)d_in[6];
    const float* Wk   = (const float*)d_in[7];
    const float* bk   = (const float*)d_in[8];
    const float* Wv   = (const float*)d_in[9];
    const float* bv   = (const float*)d_in[10];
    float* out = (float*)d_out;

    unsigned short* ws = (unsigned short*)d_ws;
    unsigned short* Qo = ws + OFF_Q;    // [bh][s][32] bf16
    unsigned short* Kf = ws + OFF_K;    // frag-native K
    unsigned short* Vf = ws + OFF_V;    // frag-native V (em-scaled)
    unsigned short* Wt = ws + OFF_W;    // [2][3][128][128] split bf16
    unsigned short* Em = ws + OFF_E;    // [b][s] bf16 exp(mask)

    wprep<<<dim3(4, 4, 4), 256, 0, stream>>>(Wq, Wk, Wv, mask, Wt, Em);
    qkv_mfma<<<dim3(BS_ / 32, 2, 3), 256, 0, stream>>>(Xq, Xk, Xv, Wt, mask,
                                                       bq, bk, bv, Qo, Kf, Vf);
    flash_mfma<<<dim3(1024), 512, 0, stream>>>(Qo, Kf, Vf, Em, hm, out);
}

// Round 16
// 52.660 us; speedup vs baseline: 1.3928x; 1.0279x over previous
//
#include <hip/hip_runtime.h>
#include <hip/hip_bf16.h>
#include <math.h>

#define B_ 8
#define S_ 2048
#define H_ 4
#define DH_ 32
#define D_ 128
#define BS_ (B_ * S_)
#define LOG2E 1.4426950408889634f
#define QSCALE (0.17677669529663687f * LOG2E)

typedef float f32x4  __attribute__((ext_vector_type(4)));
typedef float f32x16 __attribute__((ext_vector_type(16)));
typedef short s16x8  __attribute__((ext_vector_type(8)));

__device__ __forceinline__ unsigned short bf(float x) {
    return __builtin_bit_cast(unsigned short, __float2bfloat16(x));
}
__device__ __forceinline__ float bf2f(unsigned short u) {
    return __builtin_bit_cast(float, (unsigned int)u << 16);
}
// v_cvt_pk_bf16_f32: dst.lo = bf16(a), dst.hi = bf16(b)  (1 VALU instr)
__device__ __forceinline__ unsigned int pk2(float a, float b) {
    unsigned int r;
    asm("v_cvt_pk_bf16_f32 %0, %1, %2" : "=v"(r) : "v"(a), "v"(b));
    return r;
}
// v_permlane32_swap_b32: a' = [a_lo | b_lo], b' = [a_hi | b_hi]
__device__ __forceinline__ void pswap(unsigned int& a, unsigned int& b) {
    asm volatile("v_permlane32_swap_b32 %0, %1" : "+v"(a), "+v"(b));
}
__device__ __forceinline__ void gll16(const void* g, void* l) {
    __builtin_amdgcn_global_load_lds(
        (const __attribute__((address_space(1))) unsigned int*)(g),
        (__attribute__((address_space(3))) unsigned int*)(l), 16, 0, 0);
}

// ws element offsets (unsigned short units) — sized, non-overlapping:
// Qo 2097152 | Kf 2097152 | Vf 2097152 | Wt 98304 | Em 16384  = 12.81 MB
#define OFF_Q  0u
#define OFF_K  2097152u
#define OFF_V  4194304u
#define OFF_W  6291456u
#define OFF_E  6389760u

// ---------------------------------------------------------------------------
// Kernel 0: W -> Wt (transposed, split bf16 hi/lo) + Em = exp2(mask*log2e) bf16
// grid (4,4,4), block 256.
// ---------------------------------------------------------------------------
__global__ __launch_bounds__(256) void wprep(
    const float* __restrict__ Wq, const float* __restrict__ Wk, const float* __restrict__ Wv,
    const float* __restrict__ maskg,
    unsigned short* __restrict__ Wt, unsigned short* __restrict__ Em)
{
    if (blockIdx.z == 3) {
        const int id16 = blockIdx.y * 4 + blockIdx.x;
        const int base = id16 * 1024 + threadIdx.x * 4;
        float4 m4 = *(const float4*)&maskg[base];
        ushort4 o;
        o.x = bf(__builtin_amdgcn_exp2f(m4.x * LOG2E));
        o.y = bf(__builtin_amdgcn_exp2f(m4.y * LOG2E));
        o.z = bf(__builtin_amdgcn_exp2f(m4.z * LOG2E));
        o.w = bf(__builtin_amdgcn_exp2f(m4.w * LOG2E));
        *(ushort4*)&Em[base] = o;
        return;
    }
    const float* W = (blockIdx.z == 0) ? Wq : (blockIdx.z == 1) ? Wk : Wv;
    unsigned short* Oh = Wt + (size_t)blockIdx.z * D_ * D_;
    unsigned short* Ol = Oh + 3 * D_ * D_;
    __shared__ float tf[32][36];
    const int t = threadIdx.x;
    const int kt = blockIdx.x * 32, ct = blockIdx.y * 32;
    {
        int kl = t >> 3, cl = (t & 7) * 4;
        float4 w4 = *(const float4*)&W[(size_t)(kt + kl) * D_ + ct + cl];
        tf[kl][cl + 0] = w4.x; tf[kl][cl + 1] = w4.y;
        tf[kl][cl + 2] = w4.z; tf[kl][cl + 3] = w4.w;
    }
    __syncthreads();
    {
        int cl = t >> 3, kl = (t & 7) * 4;
        ushort4 oh, ol;
        float v;
        v = tf[kl + 0][cl]; oh.x = bf(v); ol.x = bf(v - bf2f(oh.x));
        v = tf[kl + 1][cl]; oh.y = bf(v); ol.y = bf(v - bf2f(oh.y));
        v = tf[kl + 2][cl]; oh.z = bf(v); ol.z = bf(v - bf2f(oh.z));
        v = tf[kl + 3][cl]; oh.w = bf(v); ol.w = bf(v - bf2f(oh.w));
        *(ushort4*)&Oh[(size_t)(ct + cl) * D_ + kt + kl] = oh;
        *(ushort4*)&Ol[(size_t)(ct + cl) * D_ + kt + kl] = ol;
    }
}

// ---------------------------------------------------------------------------
// Kernel 1: QKV projection via split-bf16 MFMA (3 terms == fp32 accuracy),
// PERSISTENT-W: each block stages its 64 W-columns (32KB) ONCE and loops
// over 4 row-tiles of 32 (r13 staged W per 32-row block -> 100MB of L2
// traffic for a 384KB matrix; now 24MB). grid (128, 2 c-halves, 3 modes),
// block 256 = 4 waves; 3 blocks/CU (52KB LDS).
// Q out: [bh][s][32] bf16 (pre-scaled by scale*log2e).
// K out: Kf fragment-native: [bh][kb32][fr(2)][lane(64)][8]
// V out: Vf fragment-native, em-scaled: [bh][kb16][lane(64)][8]
// ---------------------------------------------------------------------------
__global__ __launch_bounds__(256) void qkv_mfma(
    const float* __restrict__ Xq, const float* __restrict__ Xk, const float* __restrict__ Xv,
    const unsigned short* __restrict__ Wt, const float* __restrict__ maskg,
    const float* __restrict__ bq, const float* __restrict__ bk, const float* __restrict__ bv,
    unsigned short* __restrict__ Qo, unsigned short* __restrict__ Kf,
    unsigned short* __restrict__ Vf)
{
    const int mode = blockIdx.z, chalf = blockIdx.y;
    const float* X; const float* bias; float scl;
    if (mode == 0)      { X = Xq; bias = bq; scl = QSCALE; }
    else if (mode == 1) { X = Xk; bias = bk; scl = 1.f; }
    else                { X = Xv; bias = bv; scl = 1.f; }
    const unsigned short* WmH = Wt + (size_t)mode * D_ * D_;
    const unsigned short* WmL = WmH + 3 * D_ * D_;

    __shared__ __align__(16) unsigned short xa[2 * 32 * 136];   // X hi/lo; reused as bounce
    __shared__ __align__(16) unsigned short wt[2 * 64 * 136];   // Wt hi/lo, 64 c-rows (once)

    const int t = threadIdx.x;
    const int w = t >> 6, lane = t & 63, lo = lane & 15, hi = lane >> 4;
    const int mf = w >> 1, nb = (w & 1) * 2;

    // ---- stage W once per block
    #pragma unroll
    for (int j = 0; j < 8; j++) {
        int idx = t + 256 * j;
        int part = idx >> 10, i2 = idx & 1023;
        int r = i2 >> 4, c16 = i2 & 15;
        const unsigned short* src = part ? WmL : WmH;
        uint4 v = *(const uint4*)&src[(size_t)(chalf * 64 + r) * D_ + c16 * 8];
        *(uint4*)&wt[part * 8704 + r * 136 + c16 * 8] = v;
    }

    for (int rt = 0; rt < 4; rt++) {
        const long row0 = ((long)blockIdx.x * 4 + rt) * 32;

        __syncthreads();   // xa free (prev iter's bounce reads done); W visible
        #pragma unroll
        for (int j = 0; j < 4; j++) {
            int idx = t + 256 * j;
            int r = idx >> 5, c4 = idx & 31;
            float4 v = *(const float4*)(X + (row0 + r) * D_ + c4 * 4);
            ushort4 ph, pl;
            ph.x = bf(v.x); pl.x = bf(v.x - bf2f(ph.x));
            ph.y = bf(v.y); pl.y = bf(v.y - bf2f(ph.y));
            ph.z = bf(v.z); pl.z = bf(v.z - bf2f(ph.z));
            ph.w = bf(v.w); pl.w = bf(v.w - bf2f(ph.w));
            *(ushort4*)&xa[r * 136 + c4 * 4] = ph;
            *(ushort4*)&xa[4352 + r * 136 + c4 * 4] = pl;
        }
        __syncthreads();

        f32x4 acc[2] = {};
        #pragma unroll
        for (int kk = 0; kk < 4; kk++) {
            const int ko = kk * 32 + hi * 8;
            s16x8 ah = *(const s16x8*)&xa[(mf * 16 + lo) * 136 + ko];
            s16x8 al = *(const s16x8*)&xa[4352 + (mf * 16 + lo) * 136 + ko];
            #pragma unroll
            for (int n2 = 0; n2 < 2; n2++) {
                const int nf = nb + n2;
                s16x8 bh2 = *(const s16x8*)&wt[(nf * 16 + lo) * 136 + ko];
                s16x8 bl2 = *(const s16x8*)&wt[8704 + (nf * 16 + lo) * 136 + ko];
                acc[n2] = __builtin_amdgcn_mfma_f32_16x16x32_bf16(ah, bh2, acc[n2], 0, 0, 0);
                acc[n2] = __builtin_amdgcn_mfma_f32_16x16x32_bf16(al, bh2, acc[n2], 0, 0, 0);
                acc[n2] = __builtin_amdgcn_mfma_f32_16x16x32_bf16(ah, bl2, acc[n2], 0, 0, 0);
            }
        }
        __syncthreads();   // xa free for bounce

        const long b_i = row0 >> 11;
        const long s0g = row0 & 2047;

        if (mode < 2) {
            #pragma unroll
            for (int n2 = 0; n2 < 2; n2++) {
                int c_l = (nb + n2) * 16 + lo;
                float bb = bias[chalf * 64 + c_l];
                #pragma unroll
                for (int r = 0; r < 4; r++) {
                    int s = mf * 16 + hi * 4 + r;
                    xa[s * 72 + c_l] = bf((acc[n2][r] + bb) * scl);
                }
            }
            __syncthreads();
            int s = t >> 3, part = t & 7;
            int c_g = chalf * 64 + part * 8;
            int h = c_g >> 5, dd = c_g & 31;
            long s_i = s0g + s;
            int bh = (int)(b_i * H_ + h);
            uint4 val = *(const uint4*)&xa[s * 72 + part * 8];
            if (mode == 0) {
                *(uint4*)(Qo + ((size_t)bh * S_ + s_i) * DH_ + dd) = val;
            } else {
                int fr = dd >> 4, hwd = (dd >> 3) & 1;
                size_t off = ((((size_t)bh * 64 + (s_i >> 5)) * 2 + fr) * 64
                              + (s_i & 31) + hwd * 32) * 8;
                *(uint4*)(Kf + off) = val;
            }
        } else {
            float emr[4];
            #pragma unroll
            for (int r = 0; r < 4; r++) {
                const int s_l = mf * 16 + hi * 4 + r;
                emr[r] = __builtin_amdgcn_exp2f(maskg[b_i * S_ + s0g + s_l] * LOG2E);
            }
            #pragma unroll
            for (int n2 = 0; n2 < 2; n2++) {
                int c_l = (nb + n2) * 16 + lo;
                float bb = bias[chalf * 64 + c_l];
                #pragma unroll
                for (int r = 0; r < 4; r++) {
                    int s = mf * 16 + hi * 4 + r;
                    xa[c_l * 68 + s] = bf((acc[n2][r] + bb) * emr[r]);
                }
            }
            __syncthreads();
            if (t < 128) {
                int c_l = t >> 1, sh2 = (t & 1) * 16;
                int c_g = chalf * 64 + c_l;
                int h = c_g >> 5, dd = c_g & 31;
                long key0 = s0g + sh2;
                int bh = (int)(b_i * H_ + h);
                size_t base = (((size_t)bh * 128 + (key0 >> 4)) * 64 + dd) * 8;
                uint2 p0 = *(const uint2*)&xa[c_l * 68 + sh2 + 0];
                uint2 p1 = *(const uint2*)&xa[c_l * 68 + sh2 + 4];
                uint2 p2 = *(const uint2*)&xa[c_l * 68 + sh2 + 8];
                uint2 p3 = *(const uint2*)&xa[c_l * 68 + sh2 + 12];
                *(uint4*)(Vf + base)       = make_uint4(p0.x, p0.y, p1.x, p1.y);  // keys 0-7
                *(uint4*)(Vf + base + 256) = make_uint4(p2.x, p2.y, p3.x, p3.y);  // keys 8-15
            }
        }
    }
}

// ---------------------------------------------------------------------------
// Kernel 2: flash attention (r15, unchanged): 32x32x16 MFMA, software-
// pipelined (QK(n+1) under exp2(n)), 3-buf counted-vmcnt block staging.
// grid 1024, block 512 = 8 waves: wave = (q-half: w>>2, key-quarter: w&3).
// ---------------------------------------------------------------------------
__global__ __launch_bounds__(512) void flash_mfma(
    const unsigned short* __restrict__ Qg, const unsigned short* __restrict__ Kfg,
    const unsigned short* __restrict__ Vfg, const unsigned short* __restrict__ Emg,
    const float* __restrict__ head_mask, float* __restrict__ Out)
{
    // shorts: K bufs [3][4096] @0 | V bufs [3][4096] @12288 | em @24576
    __shared__ __align__(16) unsigned short smem[26624];   // 53248 B

    const int t = threadIdx.x, w = t >> 6, lane = t & 63;
    const int l31 = lane & 31, hw = lane >> 5;
    const int kq = w & 3, qh = w >> 2;

    const int lid = blockIdx.x;
    const int xcd = lid & 7, ser = lid >> 3;          // blocks round-robin XCDs
    const int bh = xcd * 4 + (ser >> 5);              // 4 bh per XCD (32 total)
    const int qi = ser & 31;
    const int b = bh >> 2, h = bh & 3;
    const int q0 = qi * 64 + qh * 32;

    // em: stage full row for batch b (2048 bf16 = 4KB) into LDS once
    *(uint2*)&smem[24576 + t * 4] = *(const uint2*)(Emg + (size_t)b * S_ + t * 4);

    // Q B-fragments
    const unsigned short* qp = Qg + ((size_t)bh * S_ + q0 + l31) * DH_ + hw * 8;
    const s16x8 qf0 = *(const s16x8*)qp;
    const s16x8 qf1 = *(const s16x8*)(qp + 16);

    // staging sources: wave w stages chunk w (512 shorts = 1KB) of each tile
    const size_t kvbase = (size_t)bh * 65536;
    const unsigned short* ksrc = Kfg + kvbase + (size_t)w * 512 + (size_t)lane * 8;
    const unsigned short* vsrc = Vfg + kvbase + (size_t)w * 512 + (size_t)lane * 8;

    // prologue: stage tiles 0,1,2 into bufs 0,1,2
    #pragma unroll
    for (int p = 0; p < 3; p++) {
        gll16(ksrc + (size_t)p * 4096, &smem[p * 4096 + w * 512]);
        gll16(vsrc + (size_t)p * 4096, &smem[12288 + p * 4096 + w * 512]);
    }
    __syncthreads();   // full drain: tiles 0-2 resident + em visible

    const unsigned short* emb = &smem[24576];
    f32x16 ctx = {}, lacc = {};
    const f32x16 z16 = {};

    // prime: tile 0 fragments + QK(0)
    s16x8 vf_cur0, vf_cur1, ef_cur0, ef_cur1;
    f32x16 s_cur;
    {
        const unsigned short* kb = &smem[kq * 1024];
        const unsigned short* vb = &smem[12288 + kq * 1024];
        s16x8 k0 = *(const s16x8*)(kb + (size_t)lane * 8);
        s16x8 k1 = *(const s16x8*)(kb + 512 + (size_t)lane * 8);
        vf_cur0 = *(const s16x8*)(vb + (size_t)lane * 8);
        vf_cur1 = *(const s16x8*)(vb + 512 + (size_t)lane * 8);
        ef_cur0 = *(const s16x8*)(emb + kq * 32 + hw * 8);
        ef_cur1 = *(const s16x8*)(emb + kq * 32 + hw * 8 + 16);
        s_cur = __builtin_amdgcn_mfma_f32_32x32x16_bf16(k0, qf0, z16, 0, 0, 0);
        s_cur = __builtin_amdgcn_mfma_f32_32x32x16_bf16(k1, qf1, s_cur, 0, 0, 0);
    }

    #pragma unroll
    for (int tile = 0; tile < 16; tile++) {
        // counted wait: tile n+1's glls done; tile n+2's stay in flight
        if (tile < 14)       { asm volatile("s_waitcnt vmcnt(2)" ::: "memory"); }
        else if (tile == 14) { asm volatile("s_waitcnt vmcnt(0)" ::: "memory"); }
        __builtin_amdgcn_sched_barrier(0);
        __builtin_amdgcn_s_barrier();
        __builtin_amdgcn_sched_barrier(0);

        f32x16 s_next;
        s16x8 vf_n0, vf_n1, ef_n0, ef_n1;
        if (tile < 15) {
            // ds_read tile n+1 fragments; QK(n+1) issues on the matrix pipe
            // and runs UNDER the exp2 block below
            const int nb3 = ((tile + 1) % 3) * 4096 + kq * 1024;
            const unsigned short* kb = &smem[nb3];
            const unsigned short* vb = &smem[12288 + nb3];
            s16x8 kn0 = *(const s16x8*)(kb + (size_t)lane * 8);
            s16x8 kn1 = *(const s16x8*)(kb + 512 + (size_t)lane * 8);
            vf_n0 = *(const s16x8*)(vb + (size_t)lane * 8);
            vf_n1 = *(const s16x8*)(vb + 512 + (size_t)lane * 8);
            ef_n0 = *(const s16x8*)(emb + (tile + 1) * 128 + kq * 32 + hw * 8);
            ef_n1 = *(const s16x8*)(emb + (tile + 1) * 128 + kq * 32 + hw * 8 + 16);
            s_next = __builtin_amdgcn_mfma_f32_32x32x16_bf16(kn0, qf0, z16, 0, 0, 0);
            s_next = __builtin_amdgcn_mfma_f32_32x32x16_bf16(kn1, qf1, s_next, 0, 0, 0);

            // re-stage buf n%3 for tile n+3 (WAR-safe)
            if (tile <= 12) {
                gll16(ksrc + (size_t)(tile + 3) * 4096, &smem[(tile % 3) * 4096 + w * 512]);
                gll16(vsrc + (size_t)(tile + 3) * 4096, &smem[12288 + (tile % 3) * 4096 + w * 512]);
            }
        }

        // ---- exp2/pack/permlane on s_cur (trans/VALU; overlaps QK(n+1))
        unsigned int pd[8];
        #pragma unroll
        for (int j = 0; j < 8; j++) {
            pd[j] = pk2(__builtin_amdgcn_exp2f(s_cur[2 * j]),
                        __builtin_amdgcn_exp2f(s_cur[2 * j + 1]));
        }
        pswap(pd[0], pd[2]); pswap(pd[1], pd[3]);
        pswap(pd[4], pd[6]); pswap(pd[5], pd[7]);
        const s16x8 pa0 = __builtin_bit_cast(s16x8, make_uint4(pd[0], pd[1], pd[2], pd[3]));
        const s16x8 pa1 = __builtin_bit_cast(s16x8, make_uint4(pd[4], pd[5], pd[6], pd[7]));

        // ---- PV + l for tile n (V/em held in registers since iter n-1)
        ctx  = __builtin_amdgcn_mfma_f32_32x32x16_bf16(pa0, vf_cur0, ctx, 0, 0, 0);
        lacc = __builtin_amdgcn_mfma_f32_32x32x16_bf16(pa0, ef_cur0, lacc, 0, 0, 0);
        ctx  = __builtin_amdgcn_mfma_f32_32x32x16_bf16(pa1, vf_cur1, ctx, 0, 0, 0);
        lacc = __builtin_amdgcn_mfma_f32_32x32x16_bf16(pa1, ef_cur1, lacc, 0, 0, 0);

        if (tile < 15) {
            s_cur = s_next;
            vf_cur0 = vf_n0; vf_cur1 = vf_n1;
            ef_cur0 = ef_n0; ef_cur1 = ef_n1;
        }
    }

    // ---- merge: alias smem as float scratch (full drain + barrier first)
    __syncthreads();
    float* ms = (float*)smem;   // [2][2][64][33] floats = 33792 B < 53248 B
    #define MS(qh_, sl_, ln_, r_) ms[(((qh_) * 2 + (sl_)) * 64 + (ln_)) * 33 + (r_)]

    if (kq >= 2) {
        #pragma unroll
        for (int r = 0; r < 16; r++) {
            MS(qh, kq - 2, lane, r) = ctx[r];
            MS(qh, kq - 2, lane, 16 + r) = lacc[r];
        }
    }
    __syncthreads();
    if (kq < 2) {
        #pragma unroll
        for (int r = 0; r < 16; r++) {
            ctx[r]  += MS(qh, kq, lane, r);
            lacc[r] += MS(qh, kq, lane, 16 + r);
        }
    }
    __syncthreads();
    if (kq == 1) {
        #pragma unroll
        for (int r = 0; r < 16; r++) {
            MS(qh, 0, lane, r) = ctx[r];
            MS(qh, 0, lane, 16 + r) = lacc[r];
        }
    }
    __syncthreads();
    if (kq == 0) {
        #pragma unroll
        for (int r = 0; r < 16; r++) {
            ctx[r]  += MS(qh, 0, lane, r);
            lacc[r] += MS(qh, 0, lane, 16 + r);
        }
        const float hm = head_mask[h];
        #pragma unroll
        for (int r = 0; r < 16; r++) {
            const int qrow = (r & 3) + 8 * (r >> 2) + 4 * hw;
            Out[((size_t)b * S_ + q0 + qrow) * D_ + h * DH_ + l31] = ctx[r] * hm / lacc[r];
        }
    }
    #undef MS
}

// ---------------------------------------------------------------------------
extern "C" void kernel_launch(void* const* d_in, const int* in_sizes, int n_in,
                              void* d_out, int out_size, void* d_ws, size_t ws_size,
                              hipStream_t stream) {
    const float* Xq   = (const float*)d_in[0];
    const float* Xk   = (const float*)d_in[1];
    const float* Xv   = (const float*)d_in[2];
    const float* mask = (const float*)d_in[3];
    const float* hm   = (const float*)d_in[4];
    const float* Wq   = (const float*)d_in[5];
    const float* bq   = (const float*)d_in[6];
    const float* Wk   = (const float*)d_in[7];
    const float* bk   = (const float*)d_in[8];
    const float* Wv   = (const float*)d_in[9];
    const float* bv   = (const float*)d_in[10];
    float* out = (float*)d_out;

    unsigned short* ws = (unsigned short*)d_ws;
    unsigned short* Qo = ws + OFF_Q;    // [bh][s][32] bf16
    unsigned short* Kf = ws + OFF_K;    // frag-native K
    unsigned short* Vf = ws + OFF_V;    // frag-native V (em-scaled)
    unsigned short* Wt = ws + OFF_W;    // [2][3][128][128] split bf16
    unsigned short* Em = ws + OFF_E;    // [b][s] bf16 exp(mask)

    wprep<<<dim3(4, 4, 4), 256, 0, stream>>>(Wq, Wk, Wv, mask, Wt, Em);
    qkv_mfma<<<dim3(128, 2, 3), 256, 0, stream>>>(Xq, Xk, Xv, Wt, mask,
                                                  bq, bk, bv, Qo, Kf, Vf);
    flash_mfma<<<dim3(1024), 512, 0, stream>>>(Qo, Kf, Vf, Em, hm, out);
}